// Round 4
// baseline (891.919 us; speedup 1.0000x reference)
//
#include <hip/hip_runtime.h>
#include <hip/hip_bf16.h>
#include <math.h>

#define NND 20000      // nodes
#define NE  1000000    // edges
#define RREL 32        // relations
#define HD 128         // hidden / in dim
#define NB 8           // bases
#define NT 20000       // target edges
#define KCAT 1152      // B*IN + IN  (mb || x)

// ---------- zero init of count buffers (replaces hipMemsetAsync) ----------
__global__ __launch_bounds__(256) void k_zero(int* __restrict__ cnt,
                                              int* __restrict__ node_cnt,
                                              int* __restrict__ node_fill)
{
  int i = blockIdx.x*256 + threadIdx.x;
  if (i < NND*RREL) cnt[i] = 0;
  if (i < NND){ node_cnt[i] = 0; node_fill[i] = 0; }
}

// ---------- pass 0: etype from one-hot + per-(dst,rel) and per-dst counts ----------
__global__ __launch_bounds__(256) void k_etype(
    const float* __restrict__ ea, const int* __restrict__ ei,
    int* __restrict__ etype, int* __restrict__ cnt, int* __restrict__ node_cnt)
{
  int e = blockIdx.x*256 + threadIdx.x;
  if (e >= NE) return;
  const float4* row = (const float4*)(ea + (size_t)e*RREL);
  int bi = 0;
  #pragma unroll
  for (int q=0;q<8;q++){
    float4 v = row[q];
    if (v.x > 0.5f) bi = q*4;
    if (v.y > 0.5f) bi = q*4+1;
    if (v.z > 0.5f) bi = q*4+2;
    if (v.w > 0.5f) bi = q*4+3;
  }
  etype[e] = bi;
  int dst = ei[NE + e];
  atomicAdd(&cnt[dst*RREL + bi], 1);
  atomicAdd(&node_cnt[dst], 1);
}

__global__ __launch_bounds__(256) void k_invcnt(const int* __restrict__ cnt,
                                               float* __restrict__ inv)
{
  int i = blockIdx.x*256 + threadIdx.x;
  if (i < NND*RREL) inv[i] = 1.0f / fmaxf((float)cnt[i], 1.0f);
}

// ---------- single-block exclusive scan of node_cnt -> node_off ----------
__global__ __launch_bounds__(1024) void k_scan(const int* __restrict__ node_cnt,
                                               int* __restrict__ node_off)
{
  __shared__ int part[1024];
  int t = threadIdx.x;
  const int CH = (NND + 1023)/1024;   // 20
  int base = t*CH;
  int s = 0;
  for (int i=0;i<CH;i++){ int idx = base+i; if (idx<NND) s += node_cnt[idx]; }
  part[t] = s;
  __syncthreads();
  for (int d=1; d<1024; d<<=1){
    int v = part[t];
    int u = (t>=d) ? part[t-d] : 0;
    __syncthreads();
    part[t] = v + u;
    __syncthreads();
  }
  int run = (t==0) ? 0 : part[t-1];
  for (int i=0;i<CH;i++){ int idx=base+i; if (idx<NND){ node_off[idx]=run; run += node_cnt[idx]; } }
  if (t==1023) node_off[NND] = part[1023];
}

// ---------- counting-sort scatter: edges grouped by dst ----------
__global__ __launch_bounds__(256) void k_scatter(
    const int* __restrict__ ei, const int* __restrict__ etype,
    const int* __restrict__ node_off, int* __restrict__ node_fill,
    int2* __restrict__ sorted)
{
  int e = blockIdx.x*256 + threadIdx.x;
  if (e >= NE) return;
  int dst = ei[NE+e];
  int src = ei[e];
  int pos = node_off[dst] + atomicAdd(&node_fill[dst], 1);
  sorted[pos] = make_int2(src, etype[e]);
}

// ---------- per-node aggregation into mbx[n][b*128+i], plus x copy into cols 1024.. ----------
__global__ __launch_bounds__(64) void k_agg(
    const int2* __restrict__ sorted, const int* __restrict__ node_off,
    const float* __restrict__ inv_cnt, const float* __restrict__ comp,
    const float* __restrict__ xin, float* __restrict__ mbx)
{
  int n = blockIdx.x;
  int lane = threadIdx.x;
  float a0[NB], a1[NB];
  #pragma unroll
  for (int b=0;b<NB;b++){ a0[b]=0.f; a1[b]=0.f; }
  int p0 = node_off[n], p1 = node_off[n+1];
  const float* icr = inv_cnt + (size_t)n*RREL;
  for (int p=p0; p<p1; ++p){
    int2 se = sorted[p];
    float x0 = xin[(size_t)se.x*HD + lane];
    float x1 = xin[(size_t)se.x*HD + 64 + lane];
    float ic = icr[se.y];
    const float* cr = comp + se.y*NB;
    #pragma unroll
    for (int b=0;b<NB;b++){
      float c = cr[b]*ic;
      a0[b] += c*x0;
      a1[b] += c*x1;
    }
  }
  float* o = mbx + (size_t)n*KCAT;
  #pragma unroll
  for (int b=0;b<NB;b++){
    o[b*HD + lane]      = a0[b];
    o[b*HD + 64 + lane] = a1[b];
  }
  o[1024 + lane]      = xin[(size_t)n*HD + lane];
  o[1024 + 64 + lane] = xin[(size_t)n*HD + 64 + lane];
}

// ---------- fused layer GEMM: out = relu(mbx @ [bases;root] + bias), [N x 1152]@[1152 x 128] ----------
__global__ __launch_bounds__(256) void k_gemm(
    const float* __restrict__ A, const float* __restrict__ bases,
    const float* __restrict__ root, const float* __restrict__ bias,
    float* __restrict__ out)
{
  __shared__ float As[32*68];    // As[k][m], padded
  __shared__ float Bs[32*132];   // Bs[k][o], padded
  int t = threadIdx.x;
  int bm = blockIdx.x;
  int tc = t & 31, tr = t >> 5;
  float acc[8][4];
  #pragma unroll
  for (int q=0;q<8;q++){ acc[q][0]=0.f; acc[q][1]=0.f; acc[q][2]=0.f; acc[q][3]=0.f; }

  int am = t >> 2, akq = t & 3;
  int arow = bm*64 + am;
  int bo = t & 31, bkr = t >> 5;

  for (int kb=0; kb<KCAT/32; ++kb){
    float4 va0 = make_float4(0,0,0,0), va1 = make_float4(0,0,0,0);
    if (arow < NND){
      const float4* ap = (const float4*)(A + (size_t)arow*KCAT + kb*32 + akq*8);
      va0 = ap[0]; va1 = ap[1];
    }
    As[(akq*8+0)*68+am]=va0.x; As[(akq*8+1)*68+am]=va0.y;
    As[(akq*8+2)*68+am]=va0.z; As[(akq*8+3)*68+am]=va0.w;
    As[(akq*8+4)*68+am]=va1.x; As[(akq*8+5)*68+am]=va1.y;
    As[(akq*8+6)*68+am]=va1.z; As[(akq*8+7)*68+am]=va1.w;
    #pragma unroll
    for (int it=0; it<4; ++it){
      int kk = bkr + it*8;
      int g = kb*32 + kk;
      const float* src = (g < 1024) ? (bases + (size_t)g*HD) : (root + (size_t)(g-1024)*HD);
      float4 vb = *(const float4*)(src + bo*4);
      *(float4*)&Bs[kk*132 + bo*4] = vb;
    }
    __syncthreads();
    #pragma unroll 8
    for (int kk=0; kk<32; ++kk){
      float4 b  = *(const float4*)&Bs[kk*132 + tc*4];
      float4 a0 = *(const float4*)&As[kk*68 + tr*8];
      float4 a1 = *(const float4*)&As[kk*68 + tr*8 + 4];
      float a[8] = {a0.x,a0.y,a0.z,a0.w,a1.x,a1.y,a1.z,a1.w};
      #pragma unroll
      for (int q=0;q<8;q++){
        acc[q][0] += a[q]*b.x;
        acc[q][1] += a[q]*b.y;
        acc[q][2] += a[q]*b.z;
        acc[q][3] += a[q]*b.w;
      }
    }
    __syncthreads();
  }
  float4 bi = *(const float4*)(bias + tc*4);
  #pragma unroll
  for (int q=0;q<8;++q){
    int row = bm*64 + tr*8 + q;
    if (row < NND){
      float4 o;
      o.x = fmaxf(acc[q][0]+bi.x, 0.f);
      o.y = fmaxf(acc[q][1]+bi.y, 0.f);
      o.z = fmaxf(acc[q][2]+bi.z, 0.f);
      o.w = fmaxf(acc[q][3]+bi.w, 0.f);
      *(float4*)(out + (size_t)row*HD + tc*4) = o;
    }
  }
}

// ---------- transpose R once: Rt[j][i] = R[i][j] ----------
__global__ __launch_bounds__(256) void k_tR(const float* __restrict__ Rm,
                                            float* __restrict__ Rt)
{
  int idx = blockIdx.x*256 + threadIdx.x;   // 16384 elems, 64 blocks
  if (idx >= HD*HD) return;
  int i = idx >> 7, j = idx & 127;
  Rt[(size_t)j*HD + i] = Rm[(size_t)i*HD + j];
}

// ---------- DEDICOM decoder as fused batched GEMM ----------
// block (bm, r): edges [bm*64, bm*64+64), relation r.
//   T[e][i] = sum_j (x2[e][j]*D[r][j]) * Rt[j][i]   (64x128 GEMM, K=128)
//   out[e][r] = sigmoid( sum_i x1[e][i]*D[r][i]*T[e][i] )
__global__ __launch_bounds__(256) void k_dec2(
    const float* __restrict__ h2, const int* __restrict__ tgt,
    const float* __restrict__ Rt, const float* __restrict__ D,
    float* __restrict__ out)
{
  __shared__ float As[32*68];    // As[k][e]
  __shared__ float Bs[32*132];   // Bs[k][i]
  __shared__ float Ds[128];
  __shared__ float red[32*66];   // red[i-group][e_local]
  int t = threadIdx.x;
  int bm = blockIdx.x;
  int r  = blockIdx.y;

  if (t < 32) *(float4*)&Ds[t*4] = *(const float4*)(D + (size_t)r*HD + t*4);
  __syncthreads();

  int tc = t & 31, tr = t >> 5;
  float acc[8][4];
  #pragma unroll
  for (int q=0;q<8;q++){ acc[q][0]=0.f; acc[q][1]=0.f; acc[q][2]=0.f; acc[q][3]=0.f; }

  int am = t >> 2, akq = t & 3;
  int eg = bm*64 + am;
  bool okA = (eg < NT);
  int n1 = okA ? tgt[NT + eg] : 0;
  int bo = t & 31, bkr = t >> 5;

  for (int kb=0; kb<4; ++kb){
    int kbase = kb*32 + akq*8;
    float4 va0 = make_float4(0,0,0,0), va1 = make_float4(0,0,0,0);
    if (okA){
      const float4* ap = (const float4*)(h2 + (size_t)n1*HD + kbase);
      va0 = ap[0]; va1 = ap[1];
    }
    va0.x *= Ds[kbase+0]; va0.y *= Ds[kbase+1]; va0.z *= Ds[kbase+2]; va0.w *= Ds[kbase+3];
    va1.x *= Ds[kbase+4]; va1.y *= Ds[kbase+5]; va1.z *= Ds[kbase+6]; va1.w *= Ds[kbase+7];
    As[(akq*8+0)*68+am]=va0.x; As[(akq*8+1)*68+am]=va0.y;
    As[(akq*8+2)*68+am]=va0.z; As[(akq*8+3)*68+am]=va0.w;
    As[(akq*8+4)*68+am]=va1.x; As[(akq*8+5)*68+am]=va1.y;
    As[(akq*8+6)*68+am]=va1.z; As[(akq*8+7)*68+am]=va1.w;
    #pragma unroll
    for (int it=0; it<4; ++it){
      int kk = bkr + it*8;
      int j = kb*32 + kk;
      *(float4*)&Bs[kk*132 + bo*4] = *(const float4*)(Rt + (size_t)j*HD + bo*4);
    }
    __syncthreads();
    #pragma unroll 8
    for (int kk=0; kk<32; ++kk){
      float4 b  = *(const float4*)&Bs[kk*132 + tc*4];
      float4 a0 = *(const float4*)&As[kk*68 + tr*8];
      float4 a1 = *(const float4*)&As[kk*68 + tr*8 + 4];
      float a[8] = {a0.x,a0.y,a0.z,a0.w,a1.x,a1.y,a1.z,a1.w};
      #pragma unroll
      for (int q=0;q<8;q++){
        acc[q][0] += a[q]*b.x;
        acc[q][1] += a[q]*b.y;
        acc[q][2] += a[q]*b.z;
        acc[q][3] += a[q]*b.w;
      }
    }
    __syncthreads();
  }
  // contraction: out[e][r] = sigmoid( sum_i u[e][i]*Ds[i]*T[e][i] )
  float4 dv = *(const float4*)&Ds[tc*4];
  #pragma unroll
  for (int q=0;q<8;++q){
    int eg2 = bm*64 + tr*8 + q;
    float s = 0.f;
    if (eg2 < NT){
      int n0 = tgt[eg2];
      float4 u = *(const float4*)(h2 + (size_t)n0*HD + tc*4);
      s = u.x*dv.x*acc[q][0] + u.y*dv.y*acc[q][1]
        + u.z*dv.z*acc[q][2] + u.w*dv.w*acc[q][3];
    }
    red[tc*66 + tr*8 + q] = s;
  }
  __syncthreads();
  if (t < 64){
    float s = 0.f;
    #pragma unroll
    for (int g=0; g<32; ++g) s += red[g*66 + t];
    int eg2 = bm*64 + t;
    if (eg2 < NT) out[(size_t)eg2*RREL + r] = 1.f/(1.f+expf(-s));
  }
}

extern "C" void kernel_launch(void* const* d_in, const int* in_sizes, int n_in,
                              void* d_out, int out_size, void* d_ws, size_t ws_size,
                              hipStream_t stream)
{
  const float* x      = (const float*)d_in[0];
  const int*   ei     = (const int*)d_in[1];     // int32! (harness converts integer inputs)
  const float* ea     = (const float*)d_in[2];
  const int*   tgt    = (const int*)d_in[3];     // int32!
  const float* bases1 = (const float*)d_in[4];
  const float* comp1  = (const float*)d_in[5];
  const float* root1  = (const float*)d_in[6];
  const float* bias1  = (const float*)d_in[7];
  const float* bases2 = (const float*)d_in[8];
  const float* comp2  = (const float*)d_in[9];
  const float* root2  = (const float*)d_in[10];
  const float* bias2  = (const float*)d_in[11];
  const float* Rm     = (const float*)d_in[12];
  const float* D      = (const float*)d_in[13];
  float* out = (float*)d_out;

  char* base = (char*)d_ws;
  size_t o = 0;
  auto carve = [&](size_t bytes)->char*{
    char* p = base + o;
    o += (bytes + 255) & ~(size_t)255;
    return p;
  };
  int*   etype     = (int*)  carve((size_t)NE*4);
  int*   cnt       = (int*)  carve((size_t)NND*RREL*4);
  float* inv_cnt   = (float*)carve((size_t)NND*RREL*4);
  int*   node_cnt  = (int*)  carve((size_t)NND*4);
  int*   node_fill = (int*)  carve((size_t)NND*4);
  int*   node_off  = (int*)  carve((size_t)(NND+1)*4);
  int2*  sorted    = (int2*) carve((size_t)NE*8);
  float* mbx       = (float*)carve((size_t)NND*KCAT*4);
  float* h1        = (float*)carve((size_t)NND*HD*4);
  float* h2        = (float*)carve((size_t)NND*HD*4);
  float* Rt        = (float*)carve((size_t)HD*HD*4);

  if (ws_size < o) return;   // workspace too small: fail loudly (wrong output, no corruption)

  k_zero   <<<(NND*RREL+255)/256, 256, 0, stream>>>(cnt, node_cnt, node_fill);
  k_etype  <<<(NE+255)/256, 256, 0, stream>>>(ea, ei, etype, cnt, node_cnt);
  k_invcnt <<<(NND*RREL+255)/256, 256, 0, stream>>>(cnt, inv_cnt);
  k_scan   <<<1, 1024, 0, stream>>>(node_cnt, node_off);
  k_scatter<<<(NE+255)/256, 256, 0, stream>>>(ei, etype, node_off, node_fill, sorted);

  k_agg <<<NND, 64, 0, stream>>>(sorted, node_off, inv_cnt, comp1, x, mbx);
  k_gemm<<<(NND+63)/64, 256, 0, stream>>>(mbx, bases1, root1, bias1, h1);
  k_agg <<<NND, 64, 0, stream>>>(sorted, node_off, inv_cnt, comp2, h1, mbx);
  k_gemm<<<(NND+63)/64, 256, 0, stream>>>(mbx, bases2, root2, bias2, h2);

  k_tR  <<<(HD*HD+255)/256, 256, 0, stream>>>(Rm, Rt);
  dim3 dg((NT+63)/64, RREL);
  k_dec2<<<dg, 256, 0, stream>>>(h2, tgt, Rt, D, out);
}

// Round 5
// 868.385 us; speedup vs baseline: 1.0271x; 1.0271x over previous
//
#include <hip/hip_runtime.h>
#include <hip/hip_bf16.h>
#include <math.h>

#define NND 20000      // nodes
#define NE  1000000    // edges
#define RREL 32        // relations
#define HD 128         // hidden / in dim
#define NB 8           // bases
#define NT 20000       // target edges
#define KCAT 1152      // B*IN + IN  (mb || x)
#define NBLK 64        // histogram-sort blocks
#define CHUNK ((NE + NBLK - 1) / NBLK)   // 15625 edges per block (< 65536 -> u16 counts safe)

// ---------- pass 0: etype from one-hot (pure streaming, no atomics) ----------
__global__ __launch_bounds__(256) void k_etype(
    const float* __restrict__ ea, int* __restrict__ etype)
{
  int e = blockIdx.x*256 + threadIdx.x;
  if (e >= NE) return;
  const float4* row = (const float4*)(ea + (size_t)e*RREL);
  int bi = 0;
  #pragma unroll
  for (int q=0;q<8;q++){
    float4 v = row[q];
    if (v.x > 0.5f) bi = q*4;
    if (v.y > 0.5f) bi = q*4+1;
    if (v.z > 0.5f) bi = q*4+2;
    if (v.w > 0.5f) bi = q*4+3;
  }
  etype[e] = bi;
}

// ---------- per-block dst histogram (LDS, u16-packed) -> ghist[n][b] ----------
__global__ __launch_bounds__(1024) void k_hist(const int* __restrict__ ei,
                                               int* __restrict__ ghist)
{
  __shared__ int h[NND/2];   // 40 KB, two u16 counts per int
  int t = threadIdx.x, b = blockIdx.x;
  for (int i=t; i<NND/2; i+=1024) h[i] = 0;
  __syncthreads();
  int e0 = b*CHUNK, e1 = min(e0+CHUNK, NE);
  for (int e=e0+t; e<e1; e+=1024){
    int dst = ei[NE + e];
    atomicAdd(&h[dst>>1], 1 << ((dst&1)*16));
  }
  __syncthreads();
  for (int i=t; i<NND/2; i+=1024){
    int v = h[i];
    ghist[(size_t)(2*i  )*NBLK + b] = v & 0xFFFF;
    ghist[(size_t)(2*i+1)*NBLK + b] = (v >> 16) & 0xFFFF;
  }
}

// ---------- node_cnt[n] = sum_b ghist[n][b]  (wave per node, shuffle reduce) ----------
__global__ __launch_bounds__(256) void k_rowsum(const int* __restrict__ ghist,
                                                int* __restrict__ node_cnt)
{
  int t = threadIdx.x;
  int n = blockIdx.x*4 + (t>>6);
  int lane = t & 63;
  int v = ghist[(size_t)n*NBLK + lane];
  #pragma unroll
  for (int d=32; d>0; d>>=1) v += __shfl_down(v, d);
  if (lane == 0) node_cnt[n] = v;
}

// ---------- single-block exclusive scan of node_cnt -> node_off ----------
__global__ __launch_bounds__(1024) void k_scan(const int* __restrict__ node_cnt,
                                               int* __restrict__ node_off)
{
  __shared__ int part[1024];
  int t = threadIdx.x;
  const int CH = (NND + 1023)/1024;   // 20
  int base = t*CH;
  int s = 0;
  for (int i=0;i<CH;i++){ int idx = base+i; if (idx<NND) s += node_cnt[idx]; }
  part[t] = s;
  __syncthreads();
  for (int d=1; d<1024; d<<=1){
    int v = part[t];
    int u = (t>=d) ? part[t-d] : 0;
    __syncthreads();
    part[t] = v + u;
    __syncthreads();
  }
  int run = (t==0) ? 0 : part[t-1];
  for (int i=0;i<CH;i++){ int idx=base+i; if (idx<NND){ node_off[idx]=run; run += node_cnt[idx]; } }
  if (t==1023) node_off[NND] = part[1023];
}

// ---------- ghist[n][b] -> absolute scatter base: node_off[n] + excl-prefix over b ----------
__global__ __launch_bounds__(256) void k_scanB(int* __restrict__ ghist,
                                               const int* __restrict__ node_off)
{
  int t = threadIdx.x;
  int n = blockIdx.x*4 + (t>>6);
  int lane = t & 63;
  int v = ghist[(size_t)n*NBLK + lane];
  int x = v;
  #pragma unroll
  for (int d=1; d<64; d<<=1){ int y = __shfl_up(x, d); if (lane >= d) x += y; }
  ghist[(size_t)n*NBLK + lane] = node_off[n] + x - v;   // exclusive prefix
}

// ---------- scatter replay: rank via LDS atomics, no global atomics ----------
__global__ __launch_bounds__(1024) void k_scatter2(
    const int* __restrict__ ei, const int* __restrict__ etype,
    const int* __restrict__ ghist, int2* __restrict__ sorted)
{
  __shared__ int h[NND/2];
  int t = threadIdx.x, b = blockIdx.x;
  for (int i=t; i<NND/2; i+=1024) h[i] = 0;
  __syncthreads();
  int e0 = b*CHUNK, e1 = min(e0+CHUNK, NE);
  for (int e=e0+t; e<e1; e+=1024){
    int dst = ei[NE + e];
    int sh = (dst&1)*16;
    int old = atomicAdd(&h[dst>>1], 1 << sh);
    int rank = (old >> sh) & 0xFFFF;
    int pos = ghist[(size_t)dst*NBLK + b] + rank;
    sorted[pos] = make_int2(ei[e], etype[e]);
  }
}

// ---------- per-(node,rel) inverse counts from the sorted list ----------
__global__ __launch_bounds__(256) void k_cnt(const int2* __restrict__ sorted,
                                             const int* __restrict__ node_off,
                                             float* __restrict__ inv)
{
  int t = threadIdx.x;
  int n = blockIdx.x*4 + (t>>6);
  int lane = t & 63;
  int r = lane & 31, half = lane >> 5;
  int p0 = node_off[n], p1 = node_off[n+1];
  int c = 0;
  for (int p=p0+half; p<p1; p+=2) c += (sorted[p].y == r);
  c += __shfl_down(c, 32);
  if (lane < 32) inv[(size_t)n*RREL + lane] = 1.0f / fmaxf((float)c, 1.0f);
}

// ---------- per-node aggregation into mbx[n][b*128+i], plus x copy into cols 1024.. ----------
__global__ __launch_bounds__(64) void k_agg(
    const int2* __restrict__ sorted, const int* __restrict__ node_off,
    const float* __restrict__ inv_cnt, const float* __restrict__ comp,
    const float* __restrict__ xin, float* __restrict__ mbx)
{
  int n = blockIdx.x;
  int lane = threadIdx.x;
  float a0[NB], a1[NB];
  #pragma unroll
  for (int b=0;b<NB;b++){ a0[b]=0.f; a1[b]=0.f; }
  int p0 = node_off[n], p1 = node_off[n+1];
  const float* icr = inv_cnt + (size_t)n*RREL;
  for (int p=p0; p<p1; ++p){
    int2 se = sorted[p];
    float x0 = xin[(size_t)se.x*HD + lane];
    float x1 = xin[(size_t)se.x*HD + 64 + lane];
    float ic = icr[se.y];
    const float* cr = comp + se.y*NB;
    #pragma unroll
    for (int b=0;b<NB;b++){
      float c = cr[b]*ic;
      a0[b] += c*x0;
      a1[b] += c*x1;
    }
  }
  float* o = mbx + (size_t)n*KCAT;
  #pragma unroll
  for (int b=0;b<NB;b++){
    o[b*HD + lane]      = a0[b];
    o[b*HD + 64 + lane] = a1[b];
  }
  o[1024 + lane]      = xin[(size_t)n*HD + lane];
  o[1024 + 64 + lane] = xin[(size_t)n*HD + 64 + lane];
}

// ---------- fused layer GEMM: out = relu(mbx @ [bases;root] + bias), [N x 1152]@[1152 x 128] ----------
__global__ __launch_bounds__(256) void k_gemm(
    const float* __restrict__ A, const float* __restrict__ bases,
    const float* __restrict__ root, const float* __restrict__ bias,
    float* __restrict__ out)
{
  __shared__ float As[32*68];    // As[k][m], padded
  __shared__ float Bs[32*132];   // Bs[k][o], padded
  int t = threadIdx.x;
  int bm = blockIdx.x;
  int tc = t & 31, tr = t >> 5;
  float acc[8][4];
  #pragma unroll
  for (int q=0;q<8;q++){ acc[q][0]=0.f; acc[q][1]=0.f; acc[q][2]=0.f; acc[q][3]=0.f; }

  int am = t >> 2, akq = t & 3;
  int arow = bm*64 + am;
  int bo = t & 31, bkr = t >> 5;

  for (int kb=0; kb<KCAT/32; ++kb){
    float4 va0 = make_float4(0,0,0,0), va1 = make_float4(0,0,0,0);
    if (arow < NND){
      const float4* ap = (const float4*)(A + (size_t)arow*KCAT + kb*32 + akq*8);
      va0 = ap[0]; va1 = ap[1];
    }
    As[(akq*8+0)*68+am]=va0.x; As[(akq*8+1)*68+am]=va0.y;
    As[(akq*8+2)*68+am]=va0.z; As[(akq*8+3)*68+am]=va0.w;
    As[(akq*8+4)*68+am]=va1.x; As[(akq*8+5)*68+am]=va1.y;
    As[(akq*8+6)*68+am]=va1.z; As[(akq*8+7)*68+am]=va1.w;
    #pragma unroll
    for (int it=0; it<4; ++it){
      int kk = bkr + it*8;
      int g = kb*32 + kk;
      const float* src = (g < 1024) ? (bases + (size_t)g*HD) : (root + (size_t)(g-1024)*HD);
      float4 vb = *(const float4*)(src + bo*4);
      *(float4*)&Bs[kk*132 + bo*4] = vb;
    }
    __syncthreads();
    #pragma unroll 8
    for (int kk=0; kk<32; ++kk){
      float4 b  = *(const float4*)&Bs[kk*132 + tc*4];
      float4 a0 = *(const float4*)&As[kk*68 + tr*8];
      float4 a1 = *(const float4*)&As[kk*68 + tr*8 + 4];
      float a[8] = {a0.x,a0.y,a0.z,a0.w,a1.x,a1.y,a1.z,a1.w};
      #pragma unroll
      for (int q=0;q<8;q++){
        acc[q][0] += a[q]*b.x;
        acc[q][1] += a[q]*b.y;
        acc[q][2] += a[q]*b.z;
        acc[q][3] += a[q]*b.w;
      }
    }
    __syncthreads();
  }
  float4 bi = *(const float4*)(bias + tc*4);
  #pragma unroll
  for (int q=0;q<8;++q){
    int row = bm*64 + tr*8 + q;
    if (row < NND){
      float4 o;
      o.x = fmaxf(acc[q][0]+bi.x, 0.f);
      o.y = fmaxf(acc[q][1]+bi.y, 0.f);
      o.z = fmaxf(acc[q][2]+bi.z, 0.f);
      o.w = fmaxf(acc[q][3]+bi.w, 0.f);
      *(float4*)(out + (size_t)row*HD + tc*4) = o;
    }
  }
}

// ---------- transpose R once: Rt[j][i] = R[i][j] ----------
__global__ __launch_bounds__(256) void k_tR(const float* __restrict__ Rm,
                                            float* __restrict__ Rt)
{
  int idx = blockIdx.x*256 + threadIdx.x;
  if (idx >= HD*HD) return;
  int i = idx >> 7, j = idx & 127;
  Rt[(size_t)j*HD + i] = Rm[(size_t)i*HD + j];
}

// ---------- DEDICOM decoder as fused batched GEMM ----------
__global__ __launch_bounds__(256) void k_dec2(
    const float* __restrict__ h2, const int* __restrict__ tgt,
    const float* __restrict__ Rt, const float* __restrict__ D,
    float* __restrict__ out)
{
  __shared__ float As[32*68];    // As[k][e]
  __shared__ float Bs[32*132];   // Bs[k][i]
  __shared__ float Ds[128];
  __shared__ float red[32*66];   // red[i-group][e_local]
  int t = threadIdx.x;
  int bm = blockIdx.x;
  int r  = blockIdx.y;

  if (t < 32) *(float4*)&Ds[t*4] = *(const float4*)(D + (size_t)r*HD + t*4);
  __syncthreads();

  int tc = t & 31, tr = t >> 5;
  float acc[8][4];
  #pragma unroll
  for (int q=0;q<8;q++){ acc[q][0]=0.f; acc[q][1]=0.f; acc[q][2]=0.f; acc[q][3]=0.f; }

  int am = t >> 2, akq = t & 3;
  int eg = bm*64 + am;
  bool okA = (eg < NT);
  int n1 = okA ? tgt[NT + eg] : 0;
  int bo = t & 31, bkr = t >> 5;

  for (int kb=0; kb<4; ++kb){
    int kbase = kb*32 + akq*8;
    float4 va0 = make_float4(0,0,0,0), va1 = make_float4(0,0,0,0);
    if (okA){
      const float4* ap = (const float4*)(h2 + (size_t)n1*HD + kbase);
      va0 = ap[0]; va1 = ap[1];
    }
    va0.x *= Ds[kbase+0]; va0.y *= Ds[kbase+1]; va0.z *= Ds[kbase+2]; va0.w *= Ds[kbase+3];
    va1.x *= Ds[kbase+4]; va1.y *= Ds[kbase+5]; va1.z *= Ds[kbase+6]; va1.w *= Ds[kbase+7];
    As[(akq*8+0)*68+am]=va0.x; As[(akq*8+1)*68+am]=va0.y;
    As[(akq*8+2)*68+am]=va0.z; As[(akq*8+3)*68+am]=va0.w;
    As[(akq*8+4)*68+am]=va1.x; As[(akq*8+5)*68+am]=va1.y;
    As[(akq*8+6)*68+am]=va1.z; As[(akq*8+7)*68+am]=va1.w;
    #pragma unroll
    for (int it=0; it<4; ++it){
      int kk = bkr + it*8;
      int j = kb*32 + kk;
      *(float4*)&Bs[kk*132 + bo*4] = *(const float4*)(Rt + (size_t)j*HD + bo*4);
    }
    __syncthreads();
    #pragma unroll 8
    for (int kk=0; kk<32; ++kk){
      float4 b  = *(const float4*)&Bs[kk*132 + tc*4];
      float4 a0 = *(const float4*)&As[kk*68 + tr*8];
      float4 a1 = *(const float4*)&As[kk*68 + tr*8 + 4];
      float a[8] = {a0.x,a0.y,a0.z,a0.w,a1.x,a1.y,a1.z,a1.w};
      #pragma unroll
      for (int q=0;q<8;q++){
        acc[q][0] += a[q]*b.x;
        acc[q][1] += a[q]*b.y;
        acc[q][2] += a[q]*b.z;
        acc[q][3] += a[q]*b.w;
      }
    }
    __syncthreads();
  }
  float4 dv = *(const float4*)&Ds[tc*4];
  #pragma unroll
  for (int q=0;q<8;++q){
    int eg2 = bm*64 + tr*8 + q;
    float s = 0.f;
    if (eg2 < NT){
      int n0 = tgt[eg2];
      float4 u = *(const float4*)(h2 + (size_t)n0*HD + tc*4);
      s = u.x*dv.x*acc[q][0] + u.y*dv.y*acc[q][1]
        + u.z*dv.z*acc[q][2] + u.w*dv.w*acc[q][3];
    }
    red[tc*66 + tr*8 + q] = s;
  }
  __syncthreads();
  if (t < 64){
    float s = 0.f;
    #pragma unroll
    for (int g=0; g<32; ++g) s += red[g*66 + t];
    int eg2 = bm*64 + t;
    if (eg2 < NT) out[(size_t)eg2*RREL + r] = 1.f/(1.f+expf(-s));
  }
}

extern "C" void kernel_launch(void* const* d_in, const int* in_sizes, int n_in,
                              void* d_out, int out_size, void* d_ws, size_t ws_size,
                              hipStream_t stream)
{
  const float* x      = (const float*)d_in[0];
  const int*   ei     = (const int*)d_in[1];     // int32 (harness converts integer inputs)
  const float* ea     = (const float*)d_in[2];
  const int*   tgt    = (const int*)d_in[3];     // int32
  const float* bases1 = (const float*)d_in[4];
  const float* comp1  = (const float*)d_in[5];
  const float* root1  = (const float*)d_in[6];
  const float* bias1  = (const float*)d_in[7];
  const float* bases2 = (const float*)d_in[8];
  const float* comp2  = (const float*)d_in[9];
  const float* root2  = (const float*)d_in[10];
  const float* bias2  = (const float*)d_in[11];
  const float* Rm     = (const float*)d_in[12];
  const float* D      = (const float*)d_in[13];
  float* out = (float*)d_out;

  char* base = (char*)d_ws;
  size_t o = 0;
  auto carve = [&](size_t bytes)->char*{
    char* p = base + o;
    o += (bytes + 255) & ~(size_t)255;
    return p;
  };
  int*   etype     = (int*)  carve((size_t)NE*4);
  int*   ghist     = (int*)  carve((size_t)NND*NBLK*4);
  float* inv_cnt   = (float*)carve((size_t)NND*RREL*4);
  int*   node_cnt  = (int*)  carve((size_t)NND*4);
  int*   node_off  = (int*)  carve((size_t)(NND+1)*4);
  int2*  sorted    = (int2*) carve((size_t)NE*8);
  float* mbx       = (float*)carve((size_t)NND*KCAT*4);
  float* h1        = (float*)carve((size_t)NND*HD*4);
  float* h2        = (float*)carve((size_t)NND*HD*4);
  float* Rt        = (float*)carve((size_t)HD*HD*4);

  if (ws_size < o) return;   // workspace too small: fail loudly (wrong output, no corruption)

  k_etype   <<<(NE+255)/256, 256, 0, stream>>>(ea, etype);
  k_hist    <<<NBLK, 1024, 0, stream>>>(ei, ghist);
  k_rowsum  <<<NND/4, 256, 0, stream>>>(ghist, node_cnt);
  k_scan    <<<1, 1024, 0, stream>>>(node_cnt, node_off);
  k_scanB   <<<NND/4, 256, 0, stream>>>(ghist, node_off);
  k_scatter2<<<NBLK, 1024, 0, stream>>>(ei, etype, ghist, sorted);
  k_cnt     <<<NND/4, 256, 0, stream>>>(sorted, node_off, inv_cnt);

  k_agg <<<NND, 64, 0, stream>>>(sorted, node_off, inv_cnt, comp1, x, mbx);
  k_gemm<<<(NND+63)/64, 256, 0, stream>>>(mbx, bases1, root1, bias1, h1);
  k_agg <<<NND, 64, 0, stream>>>(sorted, node_off, inv_cnt, comp2, h1, mbx);
  k_gemm<<<(NND+63)/64, 256, 0, stream>>>(mbx, bases2, root2, bias2, h2);

  k_tR  <<<(HD*HD+255)/256, 256, 0, stream>>>(Rm, Rt);
  dim3 dg((NT+63)/64, RREL);
  k_dec2<<<dg, 256, 0, stream>>>(h2, tgt, Rt, D, out);
}

// Round 6
// 689.588 us; speedup vs baseline: 1.2934x; 1.2593x over previous
//
#include <hip/hip_runtime.h>
#include <hip/hip_bf16.h>
#include <math.h>

#define NND 20000      // nodes
#define NE  1000000    // edges
#define RREL 32        // relations
#define HD 128         // hidden / in dim
#define NB 8           // bases
#define NT 20000       // target edges
#define KCAT 1152      // B*IN + IN  (mb || x)
#define NBLK 64        // histogram-sort blocks
#define CHUNK ((NE + NBLK - 1) / NBLK)   // 15625 edges per block (< 65536 -> u16 counts safe)

typedef short bf16x8 __attribute__((ext_vector_type(8)));
typedef float f32x4 __attribute__((ext_vector_type(4)));

static __device__ __forceinline__ unsigned short f2bf(float f){
  union { float f; unsigned int u; } c; c.f = f;
  unsigned int r = c.u + 0x7FFF + ((c.u >> 16) & 1);   // RNE
  return (unsigned short)(r >> 16);
}

// ---------- pass 0: etype from one-hot (pure streaming, no atomics) ----------
__global__ __launch_bounds__(256) void k_etype(
    const float* __restrict__ ea, int* __restrict__ etype)
{
  int e = blockIdx.x*256 + threadIdx.x;
  if (e >= NE) return;
  const float4* row = (const float4*)(ea + (size_t)e*RREL);
  int bi = 0;
  #pragma unroll
  for (int q=0;q<8;q++){
    float4 v = row[q];
    if (v.x > 0.5f) bi = q*4;
    if (v.y > 0.5f) bi = q*4+1;
    if (v.z > 0.5f) bi = q*4+2;
    if (v.w > 0.5f) bi = q*4+3;
  }
  etype[e] = bi;
}

// ---------- per-block dst histogram (LDS, u16-packed) -> ghist[n][b] ----------
__global__ __launch_bounds__(1024) void k_hist(const int* __restrict__ ei,
                                               int* __restrict__ ghist)
{
  __shared__ int h[NND/2];   // 40 KB, two u16 counts per int
  int t = threadIdx.x, b = blockIdx.x;
  for (int i=t; i<NND/2; i+=1024) h[i] = 0;
  __syncthreads();
  int e0 = b*CHUNK, e1 = min(e0+CHUNK, NE);
  for (int e=e0+t; e<e1; e+=1024){
    int dst = ei[NE + e];
    atomicAdd(&h[dst>>1], 1 << ((dst&1)*16));
  }
  __syncthreads();
  for (int i=t; i<NND/2; i+=1024){
    int v = h[i];
    ghist[(size_t)(2*i  )*NBLK + b] = v & 0xFFFF;
    ghist[(size_t)(2*i+1)*NBLK + b] = (v >> 16) & 0xFFFF;
  }
}

// ---------- node_cnt[n] = sum_b ghist[n][b]  (wave per node, shuffle reduce) ----------
__global__ __launch_bounds__(256) void k_rowsum(const int* __restrict__ ghist,
                                                int* __restrict__ node_cnt)
{
  int t = threadIdx.x;
  int n = blockIdx.x*4 + (t>>6);
  int lane = t & 63;
  int v = ghist[(size_t)n*NBLK + lane];
  #pragma unroll
  for (int d=32; d>0; d>>=1) v += __shfl_down(v, d);
  if (lane == 0) node_cnt[n] = v;
}

// ---------- single-block exclusive scan of node_cnt -> node_off ----------
__global__ __launch_bounds__(1024) void k_scan(const int* __restrict__ node_cnt,
                                               int* __restrict__ node_off)
{
  __shared__ int part[1024];
  int t = threadIdx.x;
  const int CH = (NND + 1023)/1024;   // 20
  int base = t*CH;
  int s = 0;
  for (int i=0;i<CH;i++){ int idx = base+i; if (idx<NND) s += node_cnt[idx]; }
  part[t] = s;
  __syncthreads();
  for (int d=1; d<1024; d<<=1){
    int v = part[t];
    int u = (t>=d) ? part[t-d] : 0;
    __syncthreads();
    part[t] = v + u;
    __syncthreads();
  }
  int run = (t==0) ? 0 : part[t-1];
  for (int i=0;i<CH;i++){ int idx=base+i; if (idx<NND){ node_off[idx]=run; run += node_cnt[idx]; } }
  if (t==1023) node_off[NND] = part[1023];
}

// ---------- ghist[n][b] -> absolute scatter base: node_off[n] + excl-prefix over b ----------
__global__ __launch_bounds__(256) void k_scanB(int* __restrict__ ghist,
                                               const int* __restrict__ node_off)
{
  int t = threadIdx.x;
  int n = blockIdx.x*4 + (t>>6);
  int lane = t & 63;
  int v = ghist[(size_t)n*NBLK + lane];
  int x = v;
  #pragma unroll
  for (int d=1; d<64; d<<=1){ int y = __shfl_up(x, d); if (lane >= d) x += y; }
  ghist[(size_t)n*NBLK + lane] = node_off[n] + x - v;   // exclusive prefix
}

// ---------- scatter replay: rank via LDS atomics, no global atomics ----------
__global__ __launch_bounds__(1024) void k_scatter2(
    const int* __restrict__ ei, const int* __restrict__ etype,
    const int* __restrict__ ghist, int2* __restrict__ sorted)
{
  __shared__ int h[NND/2];
  int t = threadIdx.x, b = blockIdx.x;
  for (int i=t; i<NND/2; i+=1024) h[i] = 0;
  __syncthreads();
  int e0 = b*CHUNK, e1 = min(e0+CHUNK, NE);
  for (int e=e0+t; e<e1; e+=1024){
    int dst = ei[NE + e];
    int sh = (dst&1)*16;
    int old = atomicAdd(&h[dst>>1], 1 << sh);
    int rank = (old >> sh) & 0xFFFF;
    int pos = ghist[(size_t)dst*NBLK + b] + rank;
    sorted[pos] = make_int2(ei[e], etype[e]);
  }
}

// ---------- per-(node,rel) inverse counts from the sorted list ----------
__global__ __launch_bounds__(256) void k_cnt(const int2* __restrict__ sorted,
                                             const int* __restrict__ node_off,
                                             float* __restrict__ inv)
{
  int t = threadIdx.x;
  int n = blockIdx.x*4 + (t>>6);
  int lane = t & 63;
  int r = lane & 31, half = lane >> 5;
  int p0 = node_off[n], p1 = node_off[n+1];
  int c = 0;
  for (int p=p0+half; p<p1; p+=2) c += (sorted[p].y == r);
  c += __shfl_down(c, 32);
  if (lane < 32) inv[(size_t)n*RREL + lane] = 1.0f / fmaxf((float)c, 1.0f);
}

// ---------- per-node aggregation into mbx[n][b*128+i], plus x copy into cols 1024.. ----------
__global__ __launch_bounds__(64) void k_agg(
    const int2* __restrict__ sorted, const int* __restrict__ node_off,
    const float* __restrict__ inv_cnt, const float* __restrict__ comp,
    const float* __restrict__ xin, float* __restrict__ mbx)
{
  int n = blockIdx.x;
  int lane = threadIdx.x;
  float a0[NB], a1[NB];
  #pragma unroll
  for (int b=0;b<NB;b++){ a0[b]=0.f; a1[b]=0.f; }
  int p0 = node_off[n], p1 = node_off[n+1];
  const float* icr = inv_cnt + (size_t)n*RREL;
  for (int p=p0; p<p1; ++p){
    int2 se = sorted[p];
    float x0 = xin[(size_t)se.x*HD + lane];
    float x1 = xin[(size_t)se.x*HD + 64 + lane];
    float ic = icr[se.y];
    const float* cr = comp + se.y*NB;
    #pragma unroll
    for (int b=0;b<NB;b++){
      float c = cr[b]*ic;
      a0[b] += c*x0;
      a1[b] += c*x1;
    }
  }
  float* o = mbx + (size_t)n*KCAT;
  #pragma unroll
  for (int b=0;b<NB;b++){
    o[b*HD + lane]      = a0[b];
    o[b*HD + 64 + lane] = a1[b];
  }
  o[1024 + lane]      = xin[(size_t)n*HD + lane];
  o[1024 + 64 + lane] = xin[(size_t)n*HD + 64 + lane];
}

// ---------- fused layer GEMM: out = relu(mbx @ [bases;root] + bias), [N x 1152]@[1152 x 128] ----------
__global__ __launch_bounds__(256) void k_gemm(
    const float* __restrict__ A, const float* __restrict__ bases,
    const float* __restrict__ root, const float* __restrict__ bias,
    float* __restrict__ out)
{
  __shared__ float As[32*68];    // As[k][m], padded
  __shared__ float Bs[32*132];   // Bs[k][o], padded
  int t = threadIdx.x;
  int bm = blockIdx.x;
  int tc = t & 31, tr = t >> 5;
  float acc[8][4];
  #pragma unroll
  for (int q=0;q<8;q++){ acc[q][0]=0.f; acc[q][1]=0.f; acc[q][2]=0.f; acc[q][3]=0.f; }

  int am = t >> 2, akq = t & 3;
  int arow = bm*64 + am;
  int bo = t & 31, bkr = t >> 5;

  for (int kb=0; kb<KCAT/32; ++kb){
    float4 va0 = make_float4(0,0,0,0), va1 = make_float4(0,0,0,0);
    if (arow < NND){
      const float4* ap = (const float4*)(A + (size_t)arow*KCAT + kb*32 + akq*8);
      va0 = ap[0]; va1 = ap[1];
    }
    As[(akq*8+0)*68+am]=va0.x; As[(akq*8+1)*68+am]=va0.y;
    As[(akq*8+2)*68+am]=va0.z; As[(akq*8+3)*68+am]=va0.w;
    As[(akq*8+4)*68+am]=va1.x; As[(akq*8+5)*68+am]=va1.y;
    As[(akq*8+6)*68+am]=va1.z; As[(akq*8+7)*68+am]=va1.w;
    #pragma unroll
    for (int it=0; it<4; ++it){
      int kk = bkr + it*8;
      int g = kb*32 + kk;
      const float* src = (g < 1024) ? (bases + (size_t)g*HD) : (root + (size_t)(g-1024)*HD);
      float4 vb = *(const float4*)(src + bo*4);
      *(float4*)&Bs[kk*132 + bo*4] = vb;
    }
    __syncthreads();
    #pragma unroll 8
    for (int kk=0; kk<32; ++kk){
      float4 b  = *(const float4*)&Bs[kk*132 + tc*4];
      float4 a0 = *(const float4*)&As[kk*68 + tr*8];
      float4 a1 = *(const float4*)&As[kk*68 + tr*8 + 4];
      float a[8] = {a0.x,a0.y,a0.z,a0.w,a1.x,a1.y,a1.z,a1.w};
      #pragma unroll
      for (int q=0;q<8;q++){
        acc[q][0] += a[q]*b.x;
        acc[q][1] += a[q]*b.y;
        acc[q][2] += a[q]*b.z;
        acc[q][3] += a[q]*b.w;
      }
    }
    __syncthreads();
  }
  float4 bi = *(const float4*)(bias + tc*4);
  #pragma unroll
  for (int q=0;q<8;++q){
    int row = bm*64 + tr*8 + q;
    if (row < NND){
      float4 o;
      o.x = fmaxf(acc[q][0]+bi.x, 0.f);
      o.y = fmaxf(acc[q][1]+bi.y, 0.f);
      o.z = fmaxf(acc[q][2]+bi.z, 0.f);
      o.w = fmaxf(acc[q][3]+bi.w, 0.f);
      *(float4*)(out + (size_t)row*HD + tc*4) = o;
    }
  }
}

// ---------- precompute Ms[r][i][j] = D[r][i]*R[i][j]*D[r][j] in bf16 (1 MB) ----------
__global__ __launch_bounds__(256) void k_prep(const float* __restrict__ Rm,
                                              const float* __restrict__ D,
                                              unsigned short* __restrict__ Ms)
{
  int r = blockIdx.x, t = threadIdx.x;
  int i = blockIdx.y*16 + (t>>4);
  int j0 = (t&15)*8;
  float di = D[r*HD + i];
  float4 dj0 = *(const float4*)(D + r*HD + j0);
  float4 dj1 = *(const float4*)(D + r*HD + j0 + 4);
  float4 r0 = *(const float4*)(Rm + (size_t)i*HD + j0);
  float4 r1 = *(const float4*)(Rm + (size_t)i*HD + j0 + 4);
  unsigned int o0 = f2bf(di*dj0.x*r0.x) | ((unsigned int)f2bf(di*dj0.y*r0.y)<<16);
  unsigned int o1 = f2bf(di*dj0.z*r0.z) | ((unsigned int)f2bf(di*dj0.w*r0.w)<<16);
  unsigned int o2 = f2bf(di*dj1.x*r1.x) | ((unsigned int)f2bf(di*dj1.y*r1.y)<<16);
  unsigned int o3 = f2bf(di*dj1.z*r1.z) | ((unsigned int)f2bf(di*dj1.w*r1.w)<<16);
  *(uint4*)(Ms + (size_t)(r*HD + i)*HD + j0) = make_uint4(o0,o1,o2,o3);
}

// ---------- DEDICOM decoder via MFMA ----------
// grid (313, 4), 256 thr. Block: 64 edges, 8 relations (blockIdx.y*8+rr).
// T[i][e] = sum_j Ms_r[i][j] * v[e][j]  -> MFMA (M=i=128, N=e=64, K=j=128)
// out[e][r] = sigmoid( sum_i u[e][i] * T[i][e] )
// wave w owns i in [w*32, w*32+32) (2 M-tiles), all 4 N-tiles.
__global__ __launch_bounds__(256) void k_dec3(
    const float* __restrict__ h2, const int* __restrict__ tgt,
    const unsigned short* __restrict__ Ms, float* __restrict__ out)
{
  __shared__ __align__(16) unsigned short vb[64*136];  // v rows bf16, pad 136
  __shared__ __align__(16) float uf[64*132];           // u rows f32,  pad 132
  __shared__ __align__(16) float red[64*8];            // per-wave partials
  int t = threadIdx.x;
  int bm = blockIdx.x;
  int lane = t & 63, w = t >> 6, g = lane >> 4, c = lane & 15;

  // stage u (fp32) and v (bf16) rows of h2, gathered by tgt
  {
    int e = t >> 2, seg = t & 3;
    int eg = bm*64 + e;
    bool ok = (eg < NT);
    int n0 = ok ? tgt[eg] : 0;
    int n1 = ok ? tgt[NT + eg] : 0;
    const float4* pu = (const float4*)(h2 + (size_t)n0*HD + seg*32);
    const float4* pv = (const float4*)(h2 + (size_t)n1*HD + seg*32);
    float* ufr = uf + e*132 + seg*32;
    unsigned int* vbr = (unsigned int*)vb + e*68 + seg*16;
    #pragma unroll
    for (int q=0;q<8;q++){
      float4 u4 = ok ? pu[q] : make_float4(0,0,0,0);
      float4 v4 = ok ? pv[q] : make_float4(0,0,0,0);
      *(float4*)(ufr + q*4) = u4;
      vbr[q*2+0] = (unsigned int)f2bf(v4.x) | ((unsigned int)f2bf(v4.y)<<16);
      vbr[q*2+1] = (unsigned int)f2bf(v4.z) | ((unsigned int)f2bf(v4.w)<<16);
    }
  }
  __syncthreads();

  for (int rr=0; rr<8; ++rr){
    int r = blockIdx.y*8 + rr;
    f32x4 acc[2][4];
    #pragma unroll
    for (int mm=0;mm<2;mm++)
      #pragma unroll
      for (int nt=0;nt<4;nt++){ f32x4 z = {0.f,0.f,0.f,0.f}; acc[mm][nt] = z; }
    #pragma unroll
    for (int kk=0; kk<4; ++kk){
      int koff = kk*32 + 8*g;
      // A-frags: Ms rows (i = mt*16 + c), k-contiguous 8 bf16 (L2-resident)
      bf16x8 a0 = *(const bf16x8*)(Ms + (size_t)(r*HD + (2*w+0)*16 + c)*HD + koff);
      bf16x8 a1 = *(const bf16x8*)(Ms + (size_t)(r*HD + (2*w+1)*16 + c)*HD + koff);
      #pragma unroll
      for (int nt=0; nt<4; ++nt){
        bf16x8 b = *(const bf16x8*)&vb[(nt*16 + c)*136 + koff];
        acc[0][nt] = __builtin_amdgcn_mfma_f32_16x16x32_bf16(a0, b, acc[0][nt], 0,0,0);
        acc[1][nt] = __builtin_amdgcn_mfma_f32_16x16x32_bf16(a1, b, acc[1][nt], 0,0,0);
      }
    }
    // contraction: s[nt] = sum over this wave's i-slice of u[e][i]*T[i][e]
    float s[4];
    #pragma unroll
    for (int nt=0; nt<4; ++nt){
      int e = nt*16 + c;
      float4 u0 = *(const float4*)&uf[e*132 + (2*w+0)*16 + 4*g];
      float4 u1 = *(const float4*)&uf[e*132 + (2*w+1)*16 + 4*g];
      s[nt] = u0.x*acc[0][nt][0] + u0.y*acc[0][nt][1] + u0.z*acc[0][nt][2] + u0.w*acc[0][nt][3]
            + u1.x*acc[1][nt][0] + u1.y*acc[1][nt][1] + u1.z*acc[1][nt][2] + u1.w*acc[1][nt][3];
      s[nt] += __shfl_xor(s[nt], 16);
      s[nt] += __shfl_xor(s[nt], 32);
    }
    if (lane < 16){
      #pragma unroll
      for (int nt=0; nt<4; ++nt) red[(nt*16 + lane)*8 + w] = s[nt];
    }
    __syncthreads();
    if (t < 64){
      float4 v4 = *(const float4*)&red[t*8];
      float sum = v4.x + v4.y + v4.z + v4.w;
      int eg = bm*64 + t;
      if (eg < NT) out[(size_t)eg*RREL + r] = 1.f/(1.f+expf(-sum));
    }
    __syncthreads();
  }
}

extern "C" void kernel_launch(void* const* d_in, const int* in_sizes, int n_in,
                              void* d_out, int out_size, void* d_ws, size_t ws_size,
                              hipStream_t stream)
{
  const float* x      = (const float*)d_in[0];
  const int*   ei     = (const int*)d_in[1];     // int32 (harness converts integer inputs)
  const float* ea     = (const float*)d_in[2];
  const int*   tgt    = (const int*)d_in[3];     // int32
  const float* bases1 = (const float*)d_in[4];
  const float* comp1  = (const float*)d_in[5];
  const float* root1  = (const float*)d_in[6];
  const float* bias1  = (const float*)d_in[7];
  const float* bases2 = (const float*)d_in[8];
  const float* comp2  = (const float*)d_in[9];
  const float* root2  = (const float*)d_in[10];
  const float* bias2  = (const float*)d_in[11];
  const float* Rm     = (const float*)d_in[12];
  const float* D      = (const float*)d_in[13];
  float* out = (float*)d_out;

  char* base = (char*)d_ws;
  size_t o = 0;
  auto carve = [&](size_t bytes)->char*{
    char* p = base + o;
    o += (bytes + 255) & ~(size_t)255;
    return p;
  };
  int*   etype     = (int*)  carve((size_t)NE*4);
  int*   ghist     = (int*)  carve((size_t)NND*NBLK*4);
  float* inv_cnt   = (float*)carve((size_t)NND*RREL*4);
  int*   node_cnt  = (int*)  carve((size_t)NND*4);
  int*   node_off  = (int*)  carve((size_t)(NND+1)*4);
  int2*  sorted    = (int2*) carve((size_t)NE*8);
  float* mbx       = (float*)carve((size_t)NND*KCAT*4);
  float* h1        = (float*)carve((size_t)NND*HD*4);
  float* h2        = (float*)carve((size_t)NND*HD*4);
  unsigned short* Ms = (unsigned short*)carve((size_t)RREL*HD*HD*2);

  if (ws_size < o) return;   // workspace too small: fail loudly (wrong output, no corruption)

  k_etype   <<<(NE+255)/256, 256, 0, stream>>>(ea, etype);
  k_hist    <<<NBLK, 1024, 0, stream>>>(ei, ghist);
  k_rowsum  <<<NND/4, 256, 0, stream>>>(ghist, node_cnt);
  k_scan    <<<1, 1024, 0, stream>>>(node_cnt, node_off);
  k_scanB   <<<NND/4, 256, 0, stream>>>(ghist, node_off);
  k_scatter2<<<NBLK, 1024, 0, stream>>>(ei, etype, ghist, sorted);
  k_cnt     <<<NND/4, 256, 0, stream>>>(sorted, node_off, inv_cnt);

  k_agg <<<NND, 64, 0, stream>>>(sorted, node_off, inv_cnt, comp1, x, mbx);
  k_gemm<<<(NND+63)/64, 256, 0, stream>>>(mbx, bases1, root1, bias1, h1);
  k_agg <<<NND, 64, 0, stream>>>(sorted, node_off, inv_cnt, comp2, h1, mbx);
  k_gemm<<<(NND+63)/64, 256, 0, stream>>>(mbx, bases2, root2, bias2, h2);

  k_prep<<<dim3(RREL, 8), 256, 0, stream>>>(Rm, D, Ms);
  dim3 dg((NT+63)/64, 4);
  k_dec3<<<dg, 256, 0, stream>>>(h2, tgt, Ms, out);
}

// Round 7
// 548.107 us; speedup vs baseline: 1.6273x; 1.2581x over previous
//
#include <hip/hip_runtime.h>
#include <hip/hip_bf16.h>
#include <math.h>

#define NND 20000      // nodes
#define NE  1000000    // edges
#define RREL 32        // relations
#define HD 128         // hidden / in dim
#define NB 8           // bases
#define NT 20000       // target edges
#define KCAT 1152      // B*IN + IN  (mb || x)
#define NBLK 64        // histogram-sort blocks
#define CHUNK ((NE + NBLK - 1) / NBLK)   // 15625 edges per block (< 65536 -> u16 counts safe)

typedef short bf16x8 __attribute__((ext_vector_type(8)));
typedef float f32x4 __attribute__((ext_vector_type(4)));

static __device__ __forceinline__ unsigned short f2bf(float f){
  union { float f; unsigned int u; } c; c.f = f;
  unsigned int r = c.u + 0x7FFF + ((c.u >> 16) & 1);   // RNE
  return (unsigned short)(r >> 16);
}

// ---------- pass 0: etype from one-hot (pure streaming, no atomics) ----------
__global__ __launch_bounds__(256) void k_etype(
    const float* __restrict__ ea, int* __restrict__ etype)
{
  int e = blockIdx.x*256 + threadIdx.x;
  if (e >= NE) return;
  const float4* row = (const float4*)(ea + (size_t)e*RREL);
  int bi = 0;
  #pragma unroll
  for (int q=0;q<8;q++){
    float4 v = row[q];
    if (v.x > 0.5f) bi = q*4;
    if (v.y > 0.5f) bi = q*4+1;
    if (v.z > 0.5f) bi = q*4+2;
    if (v.w > 0.5f) bi = q*4+3;
  }
  etype[e] = bi;
}

// ---------- per-block dst histogram (LDS, u16-packed) -> ghist[n][b] ----------
__global__ __launch_bounds__(1024) void k_hist(const int* __restrict__ ei,
                                               int* __restrict__ ghist)
{
  __shared__ int h[NND/2];   // 40 KB, two u16 counts per int
  int t = threadIdx.x, b = blockIdx.x;
  for (int i=t; i<NND/2; i+=1024) h[i] = 0;
  __syncthreads();
  int e0 = b*CHUNK, e1 = min(e0+CHUNK, NE);
  for (int e=e0+t; e<e1; e+=1024){
    int dst = ei[NE + e];
    atomicAdd(&h[dst>>1], 1 << ((dst&1)*16));
  }
  __syncthreads();
  for (int i=t; i<NND/2; i+=1024){
    int v = h[i];
    ghist[(size_t)(2*i  )*NBLK + b] = v & 0xFFFF;
    ghist[(size_t)(2*i+1)*NBLK + b] = (v >> 16) & 0xFFFF;
  }
}

// ---------- node_cnt[n] = sum_b ghist[n][b]  (wave per node, shuffle reduce) ----------
__global__ __launch_bounds__(256) void k_rowsum(const int* __restrict__ ghist,
                                                int* __restrict__ node_cnt)
{
  int t = threadIdx.x;
  int n = blockIdx.x*4 + (t>>6);
  int lane = t & 63;
  int v = ghist[(size_t)n*NBLK + lane];
  #pragma unroll
  for (int d=32; d>0; d>>=1) v += __shfl_down(v, d);
  if (lane == 0) node_cnt[n] = v;
}

// ---------- single-block exclusive scan of node_cnt -> node_off ----------
__global__ __launch_bounds__(1024) void k_scan(const int* __restrict__ node_cnt,
                                               int* __restrict__ node_off)
{
  __shared__ int part[1024];
  int t = threadIdx.x;
  const int CH = (NND + 1023)/1024;   // 20
  int base = t*CH;
  int s = 0;
  for (int i=0;i<CH;i++){ int idx = base+i; if (idx<NND) s += node_cnt[idx]; }
  part[t] = s;
  __syncthreads();
  for (int d=1; d<1024; d<<=1){
    int v = part[t];
    int u = (t>=d) ? part[t-d] : 0;
    __syncthreads();
    part[t] = v + u;
    __syncthreads();
  }
  int run = (t==0) ? 0 : part[t-1];
  for (int i=0;i<CH;i++){ int idx=base+i; if (idx<NND){ node_off[idx]=run; run += node_cnt[idx]; } }
  if (t==1023) node_off[NND] = part[1023];
}

// ---------- ghist[n][b] -> absolute scatter base: node_off[n] + excl-prefix over b ----------
__global__ __launch_bounds__(256) void k_scanB(int* __restrict__ ghist,
                                               const int* __restrict__ node_off)
{
  int t = threadIdx.x;
  int n = blockIdx.x*4 + (t>>6);
  int lane = t & 63;
  int v = ghist[(size_t)n*NBLK + lane];
  int x = v;
  #pragma unroll
  for (int d=1; d<64; d<<=1){ int y = __shfl_up(x, d); if (lane >= d) x += y; }
  ghist[(size_t)n*NBLK + lane] = node_off[n] + x - v;   // exclusive prefix
}

// ---------- scatter replay: rank via LDS atomics, no global atomics ----------
__global__ __launch_bounds__(1024) void k_scatter2(
    const int* __restrict__ ei, const int* __restrict__ etype,
    const int* __restrict__ ghist, int2* __restrict__ sorted)
{
  __shared__ int h[NND/2];
  int t = threadIdx.x, b = blockIdx.x;
  for (int i=t; i<NND/2; i+=1024) h[i] = 0;
  __syncthreads();
  int e0 = b*CHUNK, e1 = min(e0+CHUNK, NE);
  for (int e=e0+t; e<e1; e+=1024){
    int dst = ei[NE + e];
    int sh = (dst&1)*16;
    int old = atomicAdd(&h[dst>>1], 1 << sh);
    int rank = (old >> sh) & 0xFFFF;
    int pos = ghist[(size_t)dst*NBLK + b] + rank;
    sorted[pos] = make_int2(ei[e], etype[e]);
  }
}

// ---------- per-(node,rel) inverse counts from the sorted list ----------
__global__ __launch_bounds__(256) void k_cnt(const int2* __restrict__ sorted,
                                             const int* __restrict__ node_off,
                                             float* __restrict__ inv)
{
  int t = threadIdx.x;
  int n = blockIdx.x*4 + (t>>6);
  int lane = t & 63;
  int r = lane & 31, half = lane >> 5;
  int p0 = node_off[n], p1 = node_off[n+1];
  int c = 0;
  for (int p=p0+half; p<p1; p+=2) c += (sorted[p].y == r);
  c += __shfl_down(c, 32);
  if (lane < 32) inv[(size_t)n*RREL + lane] = 1.0f / fmaxf((float)c, 1.0f);
}

// ---------- per-node aggregation into mbxb[n][b*128+i] (bf16), x copy into cols 1024.. ----------
__global__ __launch_bounds__(64) void k_agg(
    const int2* __restrict__ sorted, const int* __restrict__ node_off,
    const float* __restrict__ inv_cnt, const float* __restrict__ comp,
    const float* __restrict__ xin, unsigned short* __restrict__ mbxb)
{
  int n = blockIdx.x;
  int lane = threadIdx.x;
  float a0[NB], a1[NB];
  #pragma unroll
  for (int b=0;b<NB;b++){ a0[b]=0.f; a1[b]=0.f; }
  int p0 = node_off[n], p1 = node_off[n+1];
  const float* icr = inv_cnt + (size_t)n*RREL;
  for (int p=p0; p<p1; ++p){
    int2 se = sorted[p];
    float x0 = xin[(size_t)se.x*HD + lane];
    float x1 = xin[(size_t)se.x*HD + 64 + lane];
    float ic = icr[se.y];
    const float* cr = comp + se.y*NB;
    #pragma unroll
    for (int b=0;b<NB;b++){
      float c = cr[b]*ic;
      a0[b] += c*x0;
      a1[b] += c*x1;
    }
  }
  unsigned short* o = mbxb + (size_t)n*KCAT;
  #pragma unroll
  for (int b=0;b<NB;b++){
    o[b*HD + lane]      = f2bf(a0[b]);
    o[b*HD + 64 + lane] = f2bf(a1[b]);
  }
  o[1024 + lane]      = f2bf(xin[(size_t)n*HD + lane]);
  o[1024 + 64 + lane] = f2bf(xin[(size_t)n*HD + 64 + lane]);
}

// ---------- pack W^T = [bases;root]^T into bf16 [o][k] (k-contiguous) ----------
__global__ __launch_bounds__(256) void k_prepW(
    const float* __restrict__ bases, const float* __restrict__ root,
    unsigned short* __restrict__ Wt)
{
  int idx = blockIdx.x*256 + threadIdx.x;     // o*(KCAT/8) + k8
  if (idx >= HD*(KCAT/8)) return;
  int o  = idx / (KCAT/8);
  int k0 = (idx % (KCAT/8))*8;
  unsigned short tmp[8];
  #pragma unroll
  for (int q=0;q<8;q++){
    int k = k0+q;
    float v = (k < 1024) ? bases[(size_t)k*HD + o] : root[(size_t)(k-1024)*HD + o];
    tmp[q] = f2bf(v);
  }
  *(uint4*)(Wt + (size_t)o*KCAT + k0) = *(uint4*)tmp;
}

// ---------- layer GEMM via MFMA: out = relu(mbxb @ Wt^T + bias) ----------
// grid 313, 256 thr. Block: 64 node-rows. Wave w: m-frag rows bm*64+w*16+{0..15},
// all 8 o-tiles. A=[row][k] bf16 global, B=Wt[o][k] bf16 (L2), D row=4g+q col=c.
__global__ __launch_bounds__(256) void k_gemm2(
    const unsigned short* __restrict__ A, const unsigned short* __restrict__ Wt,
    const float* __restrict__ bias, float* __restrict__ out)
{
  int t = threadIdx.x, bm = blockIdx.x;
  int lane = t & 63, w = t >> 6, g = lane >> 4, c = lane & 15;
  int arowi = bm*64 + w*16 + c;
  bool okA = (arowi < NND);
  const unsigned short* arow = A + (size_t)arowi*KCAT;
  f32x4 acc[8];
  #pragma unroll
  for (int nt=0; nt<8; ++nt){ f32x4 z = {0.f,0.f,0.f,0.f}; acc[nt] = z; }
  for (int kk=0; kk<KCAT/32; ++kk){
    int koff = kk*32 + 8*g;
    bf16x8 a = {0,0,0,0,0,0,0,0};
    if (okA) a = *(const bf16x8*)(arow + koff);
    #pragma unroll
    for (int nt=0; nt<8; ++nt){
      bf16x8 b = *(const bf16x8*)(Wt + (size_t)(nt*16 + c)*KCAT + koff);
      acc[nt] = __builtin_amdgcn_mfma_f32_16x16x32_bf16(a, b, acc[nt], 0,0,0);
    }
  }
  int orow = bm*64 + w*16 + 4*g;
  #pragma unroll
  for (int nt=0; nt<8; ++nt){
    int o = nt*16 + c;
    float bi = bias[o];
    #pragma unroll
    for (int q=0; q<4; ++q){
      int rr = orow + q;
      if (rr < NND) out[(size_t)rr*HD + o] = fmaxf(acc[nt][q] + bi, 0.f);
    }
  }
}

// ---------- precompute Ms[r][i][j] = D[r][i]*R[i][j]*D[r][j] in bf16 (1 MB) ----------
__global__ __launch_bounds__(256) void k_prep(const float* __restrict__ Rm,
                                              const float* __restrict__ D,
                                              unsigned short* __restrict__ Ms)
{
  int r = blockIdx.x, t = threadIdx.x;
  int i = blockIdx.y*16 + (t>>4);
  int j0 = (t&15)*8;
  float di = D[r*HD + i];
  float4 dj0 = *(const float4*)(D + r*HD + j0);
  float4 dj1 = *(const float4*)(D + r*HD + j0 + 4);
  float4 r0 = *(const float4*)(Rm + (size_t)i*HD + j0);
  float4 r1 = *(const float4*)(Rm + (size_t)i*HD + j0 + 4);
  unsigned int o0 = f2bf(di*dj0.x*r0.x) | ((unsigned int)f2bf(di*dj0.y*r0.y)<<16);
  unsigned int o1 = f2bf(di*dj0.z*r0.z) | ((unsigned int)f2bf(di*dj0.w*r0.w)<<16);
  unsigned int o2 = f2bf(di*dj1.x*r1.x) | ((unsigned int)f2bf(di*dj1.y*r1.y)<<16);
  unsigned int o3 = f2bf(di*dj1.z*r1.z) | ((unsigned int)f2bf(di*dj1.w*r1.w)<<16);
  *(uint4*)(Ms + (size_t)(r*HD + i)*HD + j0) = make_uint4(o0,o1,o2,o3);
}

// ---------- DEDICOM decoder via MFMA ----------
__global__ __launch_bounds__(256) void k_dec3(
    const float* __restrict__ h2, const int* __restrict__ tgt,
    const unsigned short* __restrict__ Ms, float* __restrict__ out)
{
  __shared__ __align__(16) unsigned short vb[64*136];  // v rows bf16, pad 136
  __shared__ __align__(16) float uf[64*132];           // u rows f32,  pad 132
  __shared__ __align__(16) float red[64*8];            // per-wave partials
  int t = threadIdx.x;
  int bm = blockIdx.x;
  int lane = t & 63, w = t >> 6, g = lane >> 4, c = lane & 15;

  {
    int e = t >> 2, seg = t & 3;
    int eg = bm*64 + e;
    bool ok = (eg < NT);
    int n0 = ok ? tgt[eg] : 0;
    int n1 = ok ? tgt[NT + eg] : 0;
    const float4* pu = (const float4*)(h2 + (size_t)n0*HD + seg*32);
    const float4* pv = (const float4*)(h2 + (size_t)n1*HD + seg*32);
    float* ufr = uf + e*132 + seg*32;
    unsigned int* vbr = (unsigned int*)vb + e*68 + seg*16;
    #pragma unroll
    for (int q=0;q<8;q++){
      float4 u4 = ok ? pu[q] : make_float4(0,0,0,0);
      float4 v4 = ok ? pv[q] : make_float4(0,0,0,0);
      *(float4*)(ufr + q*4) = u4;
      vbr[q*2+0] = (unsigned int)f2bf(v4.x) | ((unsigned int)f2bf(v4.y)<<16);
      vbr[q*2+1] = (unsigned int)f2bf(v4.z) | ((unsigned int)f2bf(v4.w)<<16);
    }
  }
  __syncthreads();

  for (int rr=0; rr<8; ++rr){
    int r = blockIdx.y*8 + rr;
    f32x4 acc[2][4];
    #pragma unroll
    for (int mm=0;mm<2;mm++)
      #pragma unroll
      for (int nt=0;nt<4;nt++){ f32x4 z = {0.f,0.f,0.f,0.f}; acc[mm][nt] = z; }
    #pragma unroll
    for (int kk=0; kk<4; ++kk){
      int koff = kk*32 + 8*g;
      bf16x8 a0 = *(const bf16x8*)(Ms + (size_t)(r*HD + (2*w+0)*16 + c)*HD + koff);
      bf16x8 a1 = *(const bf16x8*)(Ms + (size_t)(r*HD + (2*w+1)*16 + c)*HD + koff);
      #pragma unroll
      for (int nt=0; nt<4; ++nt){
        bf16x8 b = *(const bf16x8*)&vb[(nt*16 + c)*136 + koff];
        acc[0][nt] = __builtin_amdgcn_mfma_f32_16x16x32_bf16(a0, b, acc[0][nt], 0,0,0);
        acc[1][nt] = __builtin_amdgcn_mfma_f32_16x16x32_bf16(a1, b, acc[1][nt], 0,0,0);
      }
    }
    float s[4];
    #pragma unroll
    for (int nt=0; nt<4; ++nt){
      int e = nt*16 + c;
      float4 u0 = *(const float4*)&uf[e*132 + (2*w+0)*16 + 4*g];
      float4 u1 = *(const float4*)&uf[e*132 + (2*w+1)*16 + 4*g];
      s[nt] = u0.x*acc[0][nt][0] + u0.y*acc[0][nt][1] + u0.z*acc[0][nt][2] + u0.w*acc[0][nt][3]
            + u1.x*acc[1][nt][0] + u1.y*acc[1][nt][1] + u1.z*acc[1][nt][2] + u1.w*acc[1][nt][3];
      s[nt] += __shfl_xor(s[nt], 16);
      s[nt] += __shfl_xor(s[nt], 32);
    }
    if (lane < 16){
      #pragma unroll
      for (int nt=0; nt<4; ++nt) red[(nt*16 + lane)*8 + w] = s[nt];
    }
    __syncthreads();
    if (t < 64){
      float4 v4 = *(const float4*)&red[t*8];
      float sum = v4.x + v4.y + v4.z + v4.w;
      int eg = bm*64 + t;
      if (eg < NT) out[(size_t)eg*RREL + r] = 1.f/(1.f+expf(-sum));
    }
    __syncthreads();
  }
}

extern "C" void kernel_launch(void* const* d_in, const int* in_sizes, int n_in,
                              void* d_out, int out_size, void* d_ws, size_t ws_size,
                              hipStream_t stream)
{
  const float* x      = (const float*)d_in[0];
  const int*   ei     = (const int*)d_in[1];     // int32 (harness converts integer inputs)
  const float* ea     = (const float*)d_in[2];
  const int*   tgt    = (const int*)d_in[3];     // int32
  const float* bases1 = (const float*)d_in[4];
  const float* comp1  = (const float*)d_in[5];
  const float* root1  = (const float*)d_in[6];
  const float* bias1  = (const float*)d_in[7];
  const float* bases2 = (const float*)d_in[8];
  const float* comp2  = (const float*)d_in[9];
  const float* root2  = (const float*)d_in[10];
  const float* bias2  = (const float*)d_in[11];
  const float* Rm     = (const float*)d_in[12];
  const float* D      = (const float*)d_in[13];
  float* out = (float*)d_out;

  char* base = (char*)d_ws;
  size_t o = 0;
  auto carve = [&](size_t bytes)->char*{
    char* p = base + o;
    o += (bytes + 255) & ~(size_t)255;
    return p;
  };
  int*   etype     = (int*)  carve((size_t)NE*4);
  int*   ghist     = (int*)  carve((size_t)NND*NBLK*4);
  float* inv_cnt   = (float*)carve((size_t)NND*RREL*4);
  int*   node_cnt  = (int*)  carve((size_t)NND*4);
  int*   node_off  = (int*)  carve((size_t)(NND+1)*4);
  int2*  sorted    = (int2*) carve((size_t)NE*8);
  unsigned short* mbxb = (unsigned short*)carve((size_t)NND*KCAT*2);
  float* h1        = (float*)carve((size_t)NND*HD*4);
  float* h2        = (float*)carve((size_t)NND*HD*4);
  unsigned short* Ms  = (unsigned short*)carve((size_t)RREL*HD*HD*2);
  unsigned short* Wt1 = (unsigned short*)carve((size_t)HD*KCAT*2);
  unsigned short* Wt2 = (unsigned short*)carve((size_t)HD*KCAT*2);

  if (ws_size < o) return;   // workspace too small: fail loudly (wrong output, no corruption)

  k_etype   <<<(NE+255)/256, 256, 0, stream>>>(ea, etype);
  k_hist    <<<NBLK, 1024, 0, stream>>>(ei, ghist);
  k_rowsum  <<<NND/4, 256, 0, stream>>>(ghist, node_cnt);
  k_scan    <<<1, 1024, 0, stream>>>(node_cnt, node_off);
  k_scanB   <<<NND/4, 256, 0, stream>>>(ghist, node_off);
  k_scatter2<<<NBLK, 1024, 0, stream>>>(ei, etype, ghist, sorted);
  k_cnt     <<<NND/4, 256, 0, stream>>>(sorted, node_off, inv_cnt);

  k_prepW<<<(HD*(KCAT/8)+255)/256, 256, 0, stream>>>(bases1, root1, Wt1);
  k_prepW<<<(HD*(KCAT/8)+255)/256, 256, 0, stream>>>(bases2, root2, Wt2);
  k_prep <<<dim3(RREL, 8), 256, 0, stream>>>(Rm, D, Ms);

  k_agg  <<<NND, 64, 0, stream>>>(sorted, node_off, inv_cnt, comp1, x, mbxb);
  k_gemm2<<<(NND+63)/64, 256, 0, stream>>>(mbxb, Wt1, bias1, h1);
  k_agg  <<<NND, 64, 0, stream>>>(sorted, node_off, inv_cnt, comp2, h1, mbxb);
  k_gemm2<<<(NND+63)/64, 256, 0, stream>>>(mbxb, Wt2, bias2, h2);

  dim3 dg((NT+63)/64, 4);
  k_dec3<<<dg, 256, 0, stream>>>(h2, tgt, Ms, out);
}

// Round 8
// 533.733 us; speedup vs baseline: 1.6711x; 1.0269x over previous
//
#include <hip/hip_runtime.h>
#include <hip/hip_bf16.h>
#include <math.h>

#define NND 20000      // nodes
#define NE  1000000    // edges
#define RREL 32        // relations
#define HD 128         // hidden / in dim
#define NB 8           // bases
#define NT 20000       // target edges
#define KCAT 1152      // B*IN + IN  (mb || x)
#define NBLK 64        // histogram-sort blocks
#define CHUNK ((NE + NBLK - 1) / NBLK)   // 15625 edges per block (< 65536 -> u16 counts safe)

typedef short bf16x8 __attribute__((ext_vector_type(8)));
typedef float f32x4 __attribute__((ext_vector_type(4)));

static __device__ __forceinline__ unsigned short f2bf(float f){
  union { float f; unsigned int u; } c; c.f = f;
  unsigned int r = c.u + 0x7FFF + ((c.u >> 16) & 1);   // RNE
  return (unsigned short)(r >> 16);
}
static __device__ __forceinline__ float bf2f(unsigned short s){
  union { unsigned int u; float f; } c; c.u = ((unsigned int)s) << 16;
  return c.f;
}

// ---------- pass 0: etype from one-hot (pure streaming, no atomics) ----------
__global__ __launch_bounds__(256) void k_etype(
    const float* __restrict__ ea, int* __restrict__ etype)
{
  int e = blockIdx.x*256 + threadIdx.x;
  if (e >= NE) return;
  const float4* row = (const float4*)(ea + (size_t)e*RREL);
  int bi = 0;
  #pragma unroll
  for (int q=0;q<8;q++){
    float4 v = row[q];
    if (v.x > 0.5f) bi = q*4;
    if (v.y > 0.5f) bi = q*4+1;
    if (v.z > 0.5f) bi = q*4+2;
    if (v.w > 0.5f) bi = q*4+3;
  }
  etype[e] = bi;
}

// ---------- per-block dst histogram (LDS, u16-packed) -> ghist[n][b] ----------
__global__ __launch_bounds__(1024) void k_hist(const int* __restrict__ ei,
                                               int* __restrict__ ghist)
{
  __shared__ int h[NND/2];   // 40 KB, two u16 counts per int
  int t = threadIdx.x, b = blockIdx.x;
  for (int i=t; i<NND/2; i+=1024) h[i] = 0;
  __syncthreads();
  int e0 = b*CHUNK, e1 = min(e0+CHUNK, NE);
  for (int e=e0+t; e<e1; e+=1024){
    int dst = ei[NE + e];
    atomicAdd(&h[dst>>1], 1 << ((dst&1)*16));
  }
  __syncthreads();
  for (int i=t; i<NND/2; i+=1024){
    int v = h[i];
    ghist[(size_t)(2*i  )*NBLK + b] = v & 0xFFFF;
    ghist[(size_t)(2*i+1)*NBLK + b] = (v >> 16) & 0xFFFF;
  }
}

// ---------- node_cnt[n] = sum_b ghist[n][b]  (wave per node, shuffle reduce) ----------
__global__ __launch_bounds__(256) void k_rowsum(const int* __restrict__ ghist,
                                                int* __restrict__ node_cnt)
{
  int t = threadIdx.x;
  int n = blockIdx.x*4 + (t>>6);
  int lane = t & 63;
  int v = ghist[(size_t)n*NBLK + lane];
  #pragma unroll
  for (int d=32; d>0; d>>=1) v += __shfl_down(v, d);
  if (lane == 0) node_cnt[n] = v;
}

// ---------- single-block exclusive scan of node_cnt -> node_off ----------
__global__ __launch_bounds__(1024) void k_scan(const int* __restrict__ node_cnt,
                                               int* __restrict__ node_off)
{
  __shared__ int part[1024];
  int t = threadIdx.x;
  const int CH = (NND + 1023)/1024;   // 20
  int base = t*CH;
  int s = 0;
  for (int i=0;i<CH;i++){ int idx = base+i; if (idx<NND) s += node_cnt[idx]; }
  part[t] = s;
  __syncthreads();
  for (int d=1; d<1024; d<<=1){
    int v = part[t];
    int u = (t>=d) ? part[t-d] : 0;
    __syncthreads();
    part[t] = v + u;
    __syncthreads();
  }
  int run = (t==0) ? 0 : part[t-1];
  for (int i=0;i<CH;i++){ int idx=base+i; if (idx<NND){ node_off[idx]=run; run += node_cnt[idx]; } }
  if (t==1023) node_off[NND] = part[1023];
}

// ---------- ghist[n][b] -> absolute scatter base: node_off[n] + excl-prefix over b ----------
__global__ __launch_bounds__(256) void k_scanB(int* __restrict__ ghist,
                                               const int* __restrict__ node_off)
{
  int t = threadIdx.x;
  int n = blockIdx.x*4 + (t>>6);
  int lane = t & 63;
  int v = ghist[(size_t)n*NBLK + lane];
  int x = v;
  #pragma unroll
  for (int d=1; d<64; d<<=1){ int y = __shfl_up(x, d); if (lane >= d) x += y; }
  ghist[(size_t)n*NBLK + lane] = node_off[n] + x - v;   // exclusive prefix
}

// ---------- scatter replay: rank via LDS atomics, no global atomics ----------
__global__ __launch_bounds__(1024) void k_scatter2(
    const int* __restrict__ ei, const int* __restrict__ etype,
    const int* __restrict__ ghist, int2* __restrict__ sorted)
{
  __shared__ int h[NND/2];
  int t = threadIdx.x, b = blockIdx.x;
  for (int i=t; i<NND/2; i+=1024) h[i] = 0;
  __syncthreads();
  int e0 = b*CHUNK, e1 = min(e0+CHUNK, NE);
  for (int e=e0+t; e<e1; e+=1024){
    int dst = ei[NE + e];
    int sh = (dst&1)*16;
    int old = atomicAdd(&h[dst>>1], 1 << sh);
    int rank = (old >> sh) & 0xFFFF;
    int pos = ghist[(size_t)dst*NBLK + b] + rank;
    sorted[pos] = make_int2(ei[e], etype[e]);
  }
}

// ---------- per-(node,rel) inverse counts from the sorted list ----------
__global__ __launch_bounds__(256) void k_cnt(const int2* __restrict__ sorted,
                                             const int* __restrict__ node_off,
                                             float* __restrict__ inv)
{
  int t = threadIdx.x;
  int n = blockIdx.x*4 + (t>>6);
  int lane = t & 63;
  int r = lane & 31, half = lane >> 5;
  int p0 = node_off[n], p1 = node_off[n+1];
  int c = 0;
  for (int p=p0+half; p<p1; p+=2) c += (sorted[p].y == r);
  c += __shfl_down(c, 32);
  if (lane < 32) inv[(size_t)n*RREL + lane] = 1.0f / fmaxf((float)c, 1.0f);
}

// ---------- cast x -> bf16 rows (for gather) ----------
__global__ __launch_bounds__(256) void k_castX(const float* __restrict__ x,
                                               unsigned short* __restrict__ xb)
{
  int i = blockIdx.x*256 + threadIdx.x;   // 8 elems per thread
  if (i >= NND*HD/8) return;
  const float4* p = (const float4*)(x + (size_t)i*8);
  float4 a = p[0], b = p[1];
  unsigned int o0 = f2bf(a.x) | ((unsigned int)f2bf(a.y)<<16);
  unsigned int o1 = f2bf(a.z) | ((unsigned int)f2bf(a.w)<<16);
  unsigned int o2 = f2bf(b.x) | ((unsigned int)f2bf(b.y)<<16);
  unsigned int o3 = f2bf(b.z) | ((unsigned int)f2bf(b.w)<<16);
  *(uint4*)(xb + (size_t)i*8) = make_uint4(o0,o1,o2,o3);
}

// ---------- per-node aggregation into mbxb[n][b*128+i] (bf16), x copy into cols 1024.. ----------
// gathers bf16 rows (256 B/row), accumulates fp32
__global__ __launch_bounds__(64) void k_agg(
    const int2* __restrict__ sorted, const int* __restrict__ node_off,
    const float* __restrict__ inv_cnt, const float* __restrict__ comp,
    const unsigned short* __restrict__ xb, unsigned short* __restrict__ mbxb)
{
  int n = blockIdx.x;
  int lane = threadIdx.x;
  float a0[NB], a1[NB];
  #pragma unroll
  for (int b=0;b<NB;b++){ a0[b]=0.f; a1[b]=0.f; }
  int p0 = node_off[n], p1 = node_off[n+1];
  const float* icr = inv_cnt + (size_t)n*RREL;
  for (int p=p0; p<p1; ++p){
    int2 se = sorted[p];
    float x0 = bf2f(xb[(size_t)se.x*HD + lane]);
    float x1 = bf2f(xb[(size_t)se.x*HD + 64 + lane]);
    float ic = icr[se.y];
    const float* cr = comp + se.y*NB;
    #pragma unroll
    for (int b=0;b<NB;b++){
      float c = cr[b]*ic;
      a0[b] += c*x0;
      a1[b] += c*x1;
    }
  }
  unsigned short* o = mbxb + (size_t)n*KCAT;
  #pragma unroll
  for (int b=0;b<NB;b++){
    o[b*HD + lane]      = f2bf(a0[b]);
    o[b*HD + 64 + lane] = f2bf(a1[b]);
  }
  o[1024 + lane]      = xb[(size_t)n*HD + lane];
  o[1024 + 64 + lane] = xb[(size_t)n*HD + 64 + lane];
}

// ---------- pack W^T = [bases;root]^T into bf16 [o][k] (k-contiguous) ----------
__global__ __launch_bounds__(256) void k_prepW(
    const float* __restrict__ bases, const float* __restrict__ root,
    unsigned short* __restrict__ Wt)
{
  int idx = blockIdx.x*256 + threadIdx.x;     // o*(KCAT/8) + k8
  if (idx >= HD*(KCAT/8)) return;
  int o  = idx / (KCAT/8);
  int k0 = (idx % (KCAT/8))*8;
  unsigned short tmp[8];
  #pragma unroll
  for (int q=0;q<8;q++){
    int k = k0+q;
    float v = (k < 1024) ? bases[(size_t)k*HD + o] : root[(size_t)(k-1024)*HD + o];
    tmp[q] = f2bf(v);
  }
  *(uint4*)(Wt + (size_t)o*KCAT + k0) = *(uint4*)tmp;
}

// ---------- layer GEMM via MFMA: out = relu(mbxb @ Wt^T + bias), fp32 + bf16 outputs ----------
__global__ __launch_bounds__(256) void k_gemm2(
    const unsigned short* __restrict__ A, const unsigned short* __restrict__ Wt,
    const float* __restrict__ bias, float* __restrict__ outF,
    unsigned short* __restrict__ outB)
{
  int t = threadIdx.x, bm = blockIdx.x;
  int lane = t & 63, w = t >> 6, g = lane >> 4, c = lane & 15;
  int arowi = bm*64 + w*16 + c;
  bool okA = (arowi < NND);
  const unsigned short* arow = A + (size_t)arowi*KCAT;
  f32x4 acc[8];
  #pragma unroll
  for (int nt=0; nt<8; ++nt){ f32x4 z = {0.f,0.f,0.f,0.f}; acc[nt] = z; }
  for (int kk=0; kk<KCAT/32; ++kk){
    int koff = kk*32 + 8*g;
    bf16x8 a = {0,0,0,0,0,0,0,0};
    if (okA) a = *(const bf16x8*)(arow + koff);
    #pragma unroll
    for (int nt=0; nt<8; ++nt){
      bf16x8 b = *(const bf16x8*)(Wt + (size_t)(nt*16 + c)*KCAT + koff);
      acc[nt] = __builtin_amdgcn_mfma_f32_16x16x32_bf16(a, b, acc[nt], 0,0,0);
    }
  }
  int orow = bm*64 + w*16 + 4*g;
  #pragma unroll
  for (int nt=0; nt<8; ++nt){
    int o = nt*16 + c;
    float bi = bias[o];
    #pragma unroll
    for (int q=0; q<4; ++q){
      int rr = orow + q;
      if (rr < NND){
        float v = fmaxf(acc[nt][q] + bi, 0.f);
        outF[(size_t)rr*HD + o] = v;
        outB[(size_t)rr*HD + o] = f2bf(v);
      }
    }
  }
}

// ---------- precompute Ms[r][i][j] = D[r][i]*R[i][j]*D[r][j] in bf16 (1 MB) ----------
__global__ __launch_bounds__(256) void k_prep(const float* __restrict__ Rm,
                                              const float* __restrict__ D,
                                              unsigned short* __restrict__ Ms)
{
  int r = blockIdx.x, t = threadIdx.x;
  int i = blockIdx.y*16 + (t>>4);
  int j0 = (t&15)*8;
  float di = D[r*HD + i];
  float4 dj0 = *(const float4*)(D + r*HD + j0);
  float4 dj1 = *(const float4*)(D + r*HD + j0 + 4);
  float4 r0 = *(const float4*)(Rm + (size_t)i*HD + j0);
  float4 r1 = *(const float4*)(Rm + (size_t)i*HD + j0 + 4);
  unsigned int o0 = f2bf(di*dj0.x*r0.x) | ((unsigned int)f2bf(di*dj0.y*r0.y)<<16);
  unsigned int o1 = f2bf(di*dj0.z*r0.z) | ((unsigned int)f2bf(di*dj0.w*r0.w)<<16);
  unsigned int o2 = f2bf(di*dj1.x*r1.x) | ((unsigned int)f2bf(di*dj1.y*r1.y)<<16);
  unsigned int o3 = f2bf(di*dj1.z*r1.z) | ((unsigned int)f2bf(di*dj1.w*r1.w)<<16);
  *(uint4*)(Ms + (size_t)(r*HD + i)*HD + j0) = make_uint4(o0,o1,o2,o3);
}

// ---------- DEDICOM decoder via MFMA (all 32 relations per block; u/v staged once) ----------
__global__ __launch_bounds__(256) void k_dec3(
    const float* __restrict__ h2, const int* __restrict__ tgt,
    const unsigned short* __restrict__ Ms, float* __restrict__ out)
{
  __shared__ __align__(16) unsigned short vb[64*136];  // v rows bf16, pad 136
  __shared__ __align__(16) float uf[64*132];           // u rows f32,  pad 132
  __shared__ __align__(16) float red[64*8];            // per-wave partials
  int t = threadIdx.x;
  int bm = blockIdx.x;
  int lane = t & 63, w = t >> 6, g = lane >> 4, c = lane & 15;

  {
    int e = t >> 2, seg = t & 3;
    int eg = bm*64 + e;
    bool ok = (eg < NT);
    int n0 = ok ? tgt[eg] : 0;
    int n1 = ok ? tgt[NT + eg] : 0;
    const float4* pu = (const float4*)(h2 + (size_t)n0*HD + seg*32);
    const float4* pv = (const float4*)(h2 + (size_t)n1*HD + seg*32);
    float* ufr = uf + e*132 + seg*32;
    unsigned int* vbr = (unsigned int*)vb + e*68 + seg*16;
    #pragma unroll
    for (int q=0;q<8;q++){
      float4 u4 = ok ? pu[q] : make_float4(0,0,0,0);
      float4 v4 = ok ? pv[q] : make_float4(0,0,0,0);
      *(float4*)(ufr + q*4) = u4;
      vbr[q*2+0] = (unsigned int)f2bf(v4.x) | ((unsigned int)f2bf(v4.y)<<16);
      vbr[q*2+1] = (unsigned int)f2bf(v4.z) | ((unsigned int)f2bf(v4.w)<<16);
    }
  }
  __syncthreads();

  for (int r=0; r<RREL; ++r){
    f32x4 acc[2][4];
    #pragma unroll
    for (int mm=0;mm<2;mm++)
      #pragma unroll
      for (int nt=0;nt<4;nt++){ f32x4 z = {0.f,0.f,0.f,0.f}; acc[mm][nt] = z; }
    #pragma unroll
    for (int kk=0; kk<4; ++kk){
      int koff = kk*32 + 8*g;
      bf16x8 a0 = *(const bf16x8*)(Ms + (size_t)(r*HD + (2*w+0)*16 + c)*HD + koff);
      bf16x8 a1 = *(const bf16x8*)(Ms + (size_t)(r*HD + (2*w+1)*16 + c)*HD + koff);
      #pragma unroll
      for (int nt=0; nt<4; ++nt){
        bf16x8 b = *(const bf16x8*)&vb[(nt*16 + c)*136 + koff];
        acc[0][nt] = __builtin_amdgcn_mfma_f32_16x16x32_bf16(a0, b, acc[0][nt], 0,0,0);
        acc[1][nt] = __builtin_amdgcn_mfma_f32_16x16x32_bf16(a1, b, acc[1][nt], 0,0,0);
      }
    }
    float s[4];
    #pragma unroll
    for (int nt=0; nt<4; ++nt){
      int e = nt*16 + c;
      float4 u0 = *(const float4*)&uf[e*132 + (2*w+0)*16 + 4*g];
      float4 u1 = *(const float4*)&uf[e*132 + (2*w+1)*16 + 4*g];
      s[nt] = u0.x*acc[0][nt][0] + u0.y*acc[0][nt][1] + u0.z*acc[0][nt][2] + u0.w*acc[0][nt][3]
            + u1.x*acc[1][nt][0] + u1.y*acc[1][nt][1] + u1.z*acc[1][nt][2] + u1.w*acc[1][nt][3];
      s[nt] += __shfl_xor(s[nt], 16);
      s[nt] += __shfl_xor(s[nt], 32);
    }
    if (lane < 16){
      #pragma unroll
      for (int nt=0; nt<4; ++nt) red[(nt*16 + lane)*8 + w] = s[nt];
    }
    __syncthreads();
    if (t < 64){
      float4 v4 = *(const float4*)&red[t*8];
      float sum = v4.x + v4.y + v4.z + v4.w;
      int eg = bm*64 + t;
      if (eg < NT) out[(size_t)eg*RREL + r] = 1.f/(1.f+expf(-sum));
    }
    __syncthreads();
  }
}

extern "C" void kernel_launch(void* const* d_in, const int* in_sizes, int n_in,
                              void* d_out, int out_size, void* d_ws, size_t ws_size,
                              hipStream_t stream)
{
  const float* x      = (const float*)d_in[0];
  const int*   ei     = (const int*)d_in[1];     // int32 (harness converts integer inputs)
  const float* ea     = (const float*)d_in[2];
  const int*   tgt    = (const int*)d_in[3];     // int32
  const float* bases1 = (const float*)d_in[4];
  const float* comp1  = (const float*)d_in[5];
  const float* root1  = (const float*)d_in[6];
  const float* bias1  = (const float*)d_in[7];
  const float* bases2 = (const float*)d_in[8];
  const float* comp2  = (const float*)d_in[9];
  const float* root2  = (const float*)d_in[10];
  const float* bias2  = (const float*)d_in[11];
  const float* Rm     = (const float*)d_in[12];
  const float* D      = (const float*)d_in[13];
  float* out = (float*)d_out;

  char* base = (char*)d_ws;
  size_t o = 0;
  auto carve = [&](size_t bytes)->char*{
    char* p = base + o;
    o += (bytes + 255) & ~(size_t)255;
    return p;
  };
  int*   etype     = (int*)  carve((size_t)NE*4);
  int*   ghist     = (int*)  carve((size_t)NND*NBLK*4);
  float* inv_cnt   = (float*)carve((size_t)NND*RREL*4);
  int*   node_cnt  = (int*)  carve((size_t)NND*4);
  int*   node_off  = (int*)  carve((size_t)(NND+1)*4);
  int2*  sorted    = (int2*) carve((size_t)NE*8);
  unsigned short* mbxb = (unsigned short*)carve((size_t)NND*KCAT*2);
  float* h1        = (float*)carve((size_t)NND*HD*4);
  float* h2        = (float*)carve((size_t)NND*HD*4);
  unsigned short* xb  = (unsigned short*)carve((size_t)NND*HD*2);
  unsigned short* h1b = (unsigned short*)carve((size_t)NND*HD*2);
  unsigned short* h2b = (unsigned short*)carve((size_t)NND*HD*2);
  unsigned short* Ms  = (unsigned short*)carve((size_t)RREL*HD*HD*2);
  unsigned short* Wt1 = (unsigned short*)carve((size_t)HD*KCAT*2);
  unsigned short* Wt2 = (unsigned short*)carve((size_t)HD*KCAT*2);

  if (ws_size < o) return;   // workspace too small: fail loudly (wrong output, no corruption)

  k_etype   <<<(NE+255)/256, 256, 0, stream>>>(ea, etype);
  k_hist    <<<NBLK, 1024, 0, stream>>>(ei, ghist);
  k_rowsum  <<<NND/4, 256, 0, stream>>>(ghist, node_cnt);
  k_scan    <<<1, 1024, 0, stream>>>(node_cnt, node_off);
  k_scanB   <<<NND/4, 256, 0, stream>>>(ghist, node_off);
  k_scatter2<<<NBLK, 1024, 0, stream>>>(ei, etype, ghist, sorted);
  k_cnt     <<<NND/4, 256, 0, stream>>>(sorted, node_off, inv_cnt);

  k_castX<<<(NND*HD/8+255)/256, 256, 0, stream>>>(x, xb);
  k_prepW<<<(HD*(KCAT/8)+255)/256, 256, 0, stream>>>(bases1, root1, Wt1);
  k_prepW<<<(HD*(KCAT/8)+255)/256, 256, 0, stream>>>(bases2, root2, Wt2);
  k_prep <<<dim3(RREL, 8), 256, 0, stream>>>(Rm, D, Ms);

  k_agg  <<<NND, 64, 0, stream>>>(sorted, node_off, inv_cnt, comp1, xb, mbxb);
  k_gemm2<<<(NND+63)/64, 256, 0, stream>>>(mbxb, Wt1, bias1, h1, h1b);
  k_agg  <<<NND, 64, 0, stream>>>(sorted, node_off, inv_cnt, comp2, h1b, mbxb);
  k_gemm2<<<(NND+63)/64, 256, 0, stream>>>(mbxb, Wt2, bias2, h2, h2b);

  k_dec3<<<(NT+63)/64, 256, 0, stream>>>(h2, tgt, Ms, out);
}